// Round 4
// baseline (495.106 us; speedup 1.0000x reference)
//
#include <hip/hip_runtime.h>
#include <hip/hip_bf16.h>
#include <math.h>

#define NTOK 8192
#define DIM 256
#define KCB 4096
#define BK 16
#define LDA 132   // 128 + 4 pad
#define NCB (KCB / 128)   // 32 col-blocks in sim GEMM
#define DELTA 1e-3f       // candidate window, raw-dot units (~6e-5 cosine)
#define MAXC 16

typedef unsigned long long ull;

// ---- float <-> order-preserving u32 ----
__device__ __forceinline__ unsigned f2ord(float f) {
    unsigned u = __float_as_uint(f);
    return (u & 0x80000000u) ? ~u : (u | 0x80000000u);
}
__device__ __forceinline__ float ord2f(unsigned u) {
    unsigned b = (u & 0x80000000u) ? (u & 0x7FFFFFFFu) : ~u;
    return __uint_as_float(b);
}

// ---- numpy float32 pairwise-sum norm over 256 contiguous elements ----
// np.linalg.norm: squares rounded fp32, add.reduce pairwise (blocksize 128,
// 8 accumulators, ((r0+r1)+(r2+r3))+((r4+r5)+(r6+r7))), n=256 -> 128+128.
__device__ float np_norm256(const float* __restrict__ a) {
    float half[2];
#pragma unroll 1
    for (int h = 0; h < 2; ++h) {
        const float* p = a + h * 128;
        float r[8];
#pragma unroll
        for (int j = 0; j < 8; ++j) r[j] = __fmul_rn(p[j], p[j]);
#pragma unroll 1
        for (int i = 8; i < 128; i += 8)
#pragma unroll
            for (int j = 0; j < 8; ++j)
                r[j] = __fadd_rn(r[j], __fmul_rn(p[i + j], p[i + j]));
        float t0 = __fadd_rn(r[0], r[1]);
        float t1 = __fadd_rn(r[2], r[3]);
        float t2 = __fadd_rn(r[4], r[5]);
        float t3 = __fadd_rn(r[6], r[7]);
        half[h] = __fadd_rn(__fadd_rn(t0, t1), __fadd_rn(t2, t3));
    }
    float s = __fadd_rn(half[0], half[1]);
    return fmaxf(sqrtf(s), 1e-12f);   // sqrtf correctly rounded (HIP default)
}

// ---- init accumulators (ws is poisoned 0xAA before every launch) ----
__global__ void init_ws(unsigned* counts, float* scal, unsigned* pmin) {
    int i = blockIdx.x * blockDim.x + threadIdx.x;
    if (i < KCB) counts[i] = 0u;
    if (i == 0) { scal[0] = 0.f; scal[1] = 0.f; scal[2] = 0.f; pmin[0] = 0xFFFFFFFFu; }
}

// ---- per-row np-emulated fp32 norms (one thread per row) ----
__global__ void np_norms(const float* __restrict__ src, float* __restrict__ nrm, int nrows) {
    int r = blockIdx.x * blockDim.x + threadIdx.x;
    if (r < nrows) nrm[r] = np_norm256(src + (size_t)r * DIM);
}

// ---- codebook: cn32 = cb/nrmc (IEEE div), sq = fp32(fp64 sum of squares) ----
__global__ void cb_apply(const float* __restrict__ cb, const float* __restrict__ nrmc,
                         float* __restrict__ cn32, float* __restrict__ sq) {
    int n = blockIdx.x, t = threadIdx.x;
    float c = cb[n * DIM + t];
    cn32[n * DIM + t] = c / nrmc[n];
    __shared__ double red[256];
    red[t] = (double)c * (double)c; __syncthreads();
    for (int s = 128; s > 0; s >>= 1) { if (t < s) red[t] += red[t + s]; __syncthreads(); }
    if (t == 0) sq[n] = (float)red[0];
}

// ---- fp32 GEMM (raw latent x cn32) + per-row top-2 per col-block ----
__global__ __launch_bounds__(256) void sim_top2(const float* __restrict__ A,
                                                const float* __restrict__ B,
                                                ull* __restrict__ keysw) {
    __shared__ float As[BK][LDA];
    __shared__ float Bs[BK][LDA];
    __shared__ ull keys2[128][16][2];
    int tid = threadIdx.x;
    int tx = tid & 15, ty = tid >> 4;
    int rowBase = blockIdx.y * 128;
    int colBase = blockIdx.x * 128;
    float acc[8][8];
#pragma unroll
    for (int r = 0; r < 8; ++r)
#pragma unroll
        for (int c = 0; c < 8; ++c) acc[r][c] = 0.f;
    int lrow = tid >> 1;
    int lk = (tid & 1) * 8;
    const float* ga = A + (rowBase + lrow) * DIM + lk;
    const float* gb = B + (colBase + lrow) * DIM + lk;
    for (int kk = 0; kk < DIM; kk += BK) {
        float4 a0 = *(const float4*)(ga + kk);
        float4 a1 = *(const float4*)(ga + kk + 4);
        float4 b0 = *(const float4*)(gb + kk);
        float4 b1 = *(const float4*)(gb + kk + 4);
        __syncthreads();
        As[lk + 0][lrow] = a0.x; As[lk + 1][lrow] = a0.y; As[lk + 2][lrow] = a0.z; As[lk + 3][lrow] = a0.w;
        As[lk + 4][lrow] = a1.x; As[lk + 5][lrow] = a1.y; As[lk + 6][lrow] = a1.z; As[lk + 7][lrow] = a1.w;
        Bs[lk + 0][lrow] = b0.x; Bs[lk + 1][lrow] = b0.y; Bs[lk + 2][lrow] = b0.z; Bs[lk + 3][lrow] = b0.w;
        Bs[lk + 4][lrow] = b1.x; Bs[lk + 5][lrow] = b1.y; Bs[lk + 6][lrow] = b1.z; Bs[lk + 7][lrow] = b1.w;
        __syncthreads();
#pragma unroll
        for (int k = 0; k < BK; ++k) {
            float4 aA = *(const float4*)&As[k][ty * 8];
            float4 aB = *(const float4*)&As[k][ty * 8 + 4];
            float4 bA = *(const float4*)&Bs[k][tx * 8];
            float4 bB = *(const float4*)&Bs[k][tx * 8 + 4];
            float av[8] = {aA.x, aA.y, aA.z, aA.w, aB.x, aB.y, aB.z, aB.w};
            float bv[8] = {bA.x, bA.y, bA.z, bA.w, bB.x, bB.y, bB.z, bB.w};
#pragma unroll
            for (int r = 0; r < 8; ++r)
#pragma unroll
                for (int c = 0; c < 8; ++c)
                    acc[r][c] = fmaf(av[r], bv[c], acc[r][c]);
        }
    }
#pragma unroll
    for (int r = 0; r < 8; ++r) {
        ull b1 = 0ull, b2 = 0ull;
#pragma unroll
        for (int c = 0; c < 8; ++c) {
            unsigned col = (unsigned)(colBase + tx * 8 + c);
            ull key = ((ull)f2ord(acc[r][c]) << 32) | (ull)(0xFFFFFFFFu - col);
            if (key > b1) { b2 = b1; b1 = key; }
            else if (key > b2) b2 = key;
        }
        keys2[ty * 8 + r][tx][0] = b1;
        keys2[ty * 8 + r][tx][1] = b2;
    }
    __syncthreads();
    if (tid < 128) {
        ull k1 = 0ull, k2 = 0ull;
#pragma unroll
        for (int j = 0; j < 16; ++j)
#pragma unroll
            for (int h = 0; h < 2; ++h) {
                ull v = keys2[tid][j][h];
                if (v > k1) { k2 = k1; k1 = v; }
                else if (v > k2) k2 = v;
            }
        int row = rowBase + tid;
        keysw[(2 * blockIdx.x + 0) * NTOK + row] = k1;
        keysw[(2 * blockIdx.x + 1) * NTOK + row] = k2;
    }
}

// ---- per-row: bit-emulate the reference's fp32 pipeline on candidates ----
// ln32[d]=x[d]/nrml (IEEE), cn32[d]=cb[d]/nrmc; cosine = sequential fp32 FMA
// chain over d=0..255 (BLAS microkernel order); hedge: mul-then-add variant;
// d32 = fl(2 - fl(2*c32)); strict min, ascending index => ties -> lowest.
__global__ __launch_bounds__(256) void argmax_resolve(const float* __restrict__ lat,
                                                      const float* __restrict__ cb,
                                                      const float* __restrict__ nrml,
                                                      const float* __restrict__ nrmc,
                                                      const ull* __restrict__ keysw,
                                                      float* __restrict__ outidx,
                                                      int* __restrict__ fidx,
                                                      unsigned* __restrict__ counts,
                                                      float* __restrict__ scal) {
    int n = blockIdx.x * 256 + threadIdx.x;
    ull k1 = 0ull;
    for (int j = 0; j < 2 * NCB; ++j) {
        ull v = keysw[j * NTOK + n];
        if (v > k1) k1 = v;
    }
    float v1 = ord2f((unsigned)(k1 >> 32));
    int i1 = (int)(0xFFFFFFFFu - (unsigned)(k1 & 0xFFFFFFFFull));
    float thresh = v1 - DELTA;
    int cand[MAXC]; int nc = 0;
    for (int j = 0; j < 2 * NCB; ++j) {
        ull v = keysw[j * NTOK + n];
        float val = ord2f((unsigned)(v >> 32));
        if (val >= thresh && nc < MAXC)
            cand[nc++] = (int)(0xFFFFFFFFu - (unsigned)(v & 0xFFFFFFFFull));
    }
    float nx = nrml[n];
    int idx; float selcos;
    if (nc <= 1) {
        idx = i1; selcos = v1 / nx;
    } else {
        // sort candidates ascending (<=16 elements)
        for (int a = 1; a < nc; ++a) {
            int key = cand[a]; int b = a - 1;
            while (b >= 0 && cand[b] > key) { cand[b + 1] = cand[b]; --b; }
            cand[b + 1] = key;
        }
        const float* x = lat + (size_t)n * DIM;
        float bestf = INFINITY, bestm = INFINITY, caf[MAXC];
        int bif = 0x7FFFFFFF, bim = 0x7FFFFFFF;
        for (int c = 0; c < nc; ++c) {
            int k = cand[c];
            const float* cr = cb + (size_t)k * DIM;
            float nk = nrmc[k];
            float af = 0.f, am = 0.f;
            for (int d = 0; d < DIM; ++d) {
                float la = x[d] / nx;       // IEEE fp32 divide
                float cv = cr[d] / nk;
                af = fmaf(la, cv, af);                       // FMA chain
                am = __fadd_rn(am, __fmul_rn(la, cv));       // mul+add chain
            }
            float df = __fsub_rn(2.0f, __fmul_rn(2.0f, af));
            float dm = __fsub_rn(2.0f, __fmul_rn(2.0f, am));
            caf[c] = af;
            if (df < bestf) { bestf = df; bif = k; }
            if (dm < bestm) { bestm = dm; bim = k; }
        }
        idx = (bif == bim) ? bif : (bif < bim ? bif : bim);
        selcos = 0.f;
        for (int c = 0; c < nc; ++c) if (cand[c] == idx) selcos = caf[c];
    }
    fidx[n] = idx;
    outidx[n] = (float)idx;
    atomicAdd(&counts[idx], 1u);
    __shared__ float red[256];
    red[threadIdx.x] = selcos; __syncthreads();
    for (int s = 128; s > 0; s >>= 1) {
        if (threadIdx.x < s) red[threadIdx.x] += red[threadIdx.x + s];
        __syncthreads();
    }
    if (threadIdx.x == 0) atomicAdd(&scal[1], red[0]);
}

// ---- codebook pairwise euclidean: upper-triangle tiles, fused sum/min ----
__global__ __launch_bounds__(256) void pairwise(const float* __restrict__ C,
                                                const float* __restrict__ sq,
                                                float* __restrict__ pairSum,
                                                unsigned* __restrict__ pairMin) {
    int ti = blockIdx.y, tj = blockIdx.x;
    if (ti > tj) return;
    __shared__ float As[BK][LDA];
    __shared__ float Bs[BK][LDA];
    int tid = threadIdx.x;
    int tx = tid & 15, ty = tid >> 4;
    int rowBase = ti * 128;
    int colBase = tj * 128;
    float acc[8][8];
#pragma unroll
    for (int r = 0; r < 8; ++r)
#pragma unroll
        for (int c = 0; c < 8; ++c) acc[r][c] = 0.f;
    int lrow = tid >> 1;
    int lk = (tid & 1) * 8;
    const float* ga = C + (rowBase + lrow) * DIM + lk;
    const float* gb = C + (colBase + lrow) * DIM + lk;
    for (int kk = 0; kk < DIM; kk += BK) {
        float4 a0 = *(const float4*)(ga + kk);
        float4 a1 = *(const float4*)(ga + kk + 4);
        float4 b0 = *(const float4*)(gb + kk);
        float4 b1 = *(const float4*)(gb + kk + 4);
        __syncthreads();
        As[lk + 0][lrow] = a0.x; As[lk + 1][lrow] = a0.y; As[lk + 2][lrow] = a0.z; As[lk + 3][lrow] = a0.w;
        As[lk + 4][lrow] = a1.x; As[lk + 5][lrow] = a1.y; As[lk + 6][lrow] = a1.z; As[lk + 7][lrow] = a1.w;
        Bs[lk + 0][lrow] = b0.x; Bs[lk + 1][lrow] = b0.y; Bs[lk + 2][lrow] = b0.z; Bs[lk + 3][lrow] = b0.w;
        Bs[lk + 4][lrow] = b1.x; Bs[lk + 5][lrow] = b1.y; Bs[lk + 6][lrow] = b1.z; Bs[lk + 7][lrow] = b1.w;
        __syncthreads();
#pragma unroll
        for (int k = 0; k < BK; ++k) {
            float4 aA = *(const float4*)&As[k][ty * 8];
            float4 aB = *(const float4*)&As[k][ty * 8 + 4];
            float4 bA = *(const float4*)&Bs[k][tx * 8];
            float4 bB = *(const float4*)&Bs[k][tx * 8 + 4];
            float av[8] = {aA.x, aA.y, aA.z, aA.w, aB.x, aB.y, aB.z, aB.w};
            float bv[8] = {bA.x, bA.y, bA.z, bA.w, bB.x, bB.y, bB.z, bB.w};
#pragma unroll
            for (int r = 0; r < 8; ++r)
#pragma unroll
                for (int c = 0; c < 8; ++c)
                    acc[r][c] = fmaf(av[r], bv[c], acc[r][c]);
        }
    }
    float sqi[8], sqj[8];
#pragma unroll
    for (int r = 0; r < 8; ++r) sqi[r] = sq[rowBase + ty * 8 + r];
#pragma unroll
    for (int c = 0; c < 8; ++c) sqj[c] = sq[colBase + tx * 8 + c];
    float lsum = 0.f, lmin = INFINITY;
#pragma unroll
    for (int r = 0; r < 8; ++r) {
        int i = rowBase + ty * 8 + r;
#pragma unroll
        for (int c = 0; c < 8; ++c) {
            int j = colBase + tx * 8 + c;
            if (i < j) {
                float d2 = sqi[r] + sqj[c] - 2.0f * acc[r][c];
                float d = sqrtf(fmaxf(d2, 0.0f));
                lsum += d;
                lmin = fminf(lmin, d);
            }
        }
    }
    __shared__ float rs[256], rm[256];
    rs[tid] = lsum; rm[tid] = lmin; __syncthreads();
    for (int s = 128; s > 0; s >>= 1) {
        if (tid < s) { rs[tid] += rs[tid + s]; rm[tid] = fminf(rm[tid], rm[tid + s]); }
        __syncthreads();
    }
    if (tid == 0) { atomicAdd(pairSum, rs[0]); atomicMin(pairMin, f2ord(rm[0])); }
}

// ---- gather quantized + mse (16 rows per block) ----
__global__ __launch_bounds__(256) void gather_out(const float* __restrict__ latent,
                                                  const float* __restrict__ codebook,
                                                  const int* __restrict__ fidx,
                                                  float* __restrict__ outq,
                                                  float* __restrict__ scal) {
    int t = threadIdx.x;
    int n0 = blockIdx.x * 16;
    float msePart = 0.f;
    for (int r = 0; r < 16; ++r) {
        int n = n0 + r;
        int idx = fidx[n];
        float q = codebook[(size_t)idx * DIM + t];
        float x = latent[(size_t)n * DIM + t];
        outq[(size_t)n * DIM + t] = q;
        float d = x - q;
        msePart = fmaf(d, d, msePart);
    }
    __shared__ float red[256];
    red[t] = msePart; __syncthreads();
    for (int s = 128; s > 0; s >>= 1) { if (t < s) red[t] += red[t + s]; __syncthreads(); }
    if (t == 0) atomicAdd(&scal[0], red[0]);
}

// ---- scalars ----
__global__ void finalize(const unsigned* __restrict__ counts, const float* __restrict__ scal,
                         const unsigned* __restrict__ pmin, float* __restrict__ outs) {
    int t = threadIdx.x;
    float h = 0.f;
    for (int k = t; k < KCB; k += 256) {
        float p = (float)counts[k] * (1.0f / (float)NTOK);
        h += p * logf(p + 1e-10f);
    }
    __shared__ float red[256];
    red[t] = h; __syncthreads();
    for (int s = 128; s > 0; s >>= 1) { if (t < s) red[t] += red[t + s]; __syncthreads(); }
    if (t == 0) {
        float mse = scal[0] / (float)(NTOK * DIM);
        outs[0] = 0.25f * mse;           // commitment_loss
        outs[1] = mse;                   // codebook_loss
        outs[2] = expf(-red[0]);         // perplexity
        outs[3] = scal[1] / (float)NTOK; // selected_cosine_sim
        outs[4] = scal[2] * 2.0f / ((float)KCB * (float)(KCB - 1)); // avg_euclidean
        outs[5] = ord2f(pmin[0]);        // min_euclidean
    }
}

extern "C" void kernel_launch(void* const* d_in, const int* in_sizes, int n_in,
                              void* d_out, int out_size, void* d_ws, size_t ws_size,
                              hipStream_t stream) {
    const float* latent = (const float*)d_in[0];    // [8192,256]
    const float* codebook = (const float*)d_in[1];  // [4096,256]
    float* out = (float*)d_out;
    float* outq = out;
    float* outidx = out + (size_t)NTOK * DIM;
    float* outs = outidx + NTOK;

    ull* keysw = (ull*)d_ws;                          // 64*8192 u64 = 4 MB (8B aligned)
    float* cn32 = (float*)(keysw + 2 * NCB * NTOK);   // 4096*256 = 4 MB
    float* nrml = cn32 + (size_t)KCB * DIM;           // 8192
    float* nrmc = nrml + NTOK;                        // 4096
    float* sq = nrmc + KCB;                           // 4096
    int* fidx = (int*)(sq + KCB);                     // 8192
    unsigned* counts = (unsigned*)(fidx + NTOK);      // 4096
    float* scal = (float*)(counts + KCB);             // [mse_sum, sel_sum, pair_sum]
    unsigned* pmin = (unsigned*)(scal + 3);

    hipLaunchKernelGGL(init_ws, dim3((KCB + 255) / 256), dim3(256), 0, stream, counts, scal, pmin);
    hipLaunchKernelGGL(np_norms, dim3(NTOK / 256), dim3(256), 0, stream, latent, nrml, NTOK);
    hipLaunchKernelGGL(np_norms, dim3(KCB / 256), dim3(256), 0, stream, codebook, nrmc, KCB);
    hipLaunchKernelGGL(cb_apply, dim3(KCB), dim3(256), 0, stream, codebook, nrmc, cn32, sq);
    hipLaunchKernelGGL(sim_top2, dim3(NCB, NTOK / 128), dim3(256), 0, stream, latent, cn32, keysw);
    hipLaunchKernelGGL(argmax_resolve, dim3(NTOK / 256), dim3(256), 0, stream,
                       latent, codebook, nrml, nrmc, keysw, outidx, fidx, counts, scal);
    hipLaunchKernelGGL(pairwise, dim3(KCB / 128, KCB / 128), dim3(256), 0, stream, codebook, sq,
                       &scal[2], pmin);
    hipLaunchKernelGGL(gather_out, dim3(NTOK / 16), dim3(256), 0, stream, latent, codebook, fidx,
                       outq, scal);
    hipLaunchKernelGGL(finalize, dim3(1), dim3(256), 0, stream, counts, scal, pmin, outs);
}